// Round 1
// baseline (361.818 us; speedup 1.0000x reference)
//
#include <hip/hip_runtime.h>

// Problem constants (from reference setup_inputs)
#define NB     64          // NUM_BINS
#define CCH    256         // channels
#define HW     20480       // 128*160
#define NBATCH 4
#define NPIX   (NBATCH*HW) // 81920

// Workspace layout (bytes):
//   sumsS  [64][256] f32 @ 0        (65536)
//   sumsT  [64][256] f32 @ 65536    (65536)
//   counts [65] int      @ 131072   (260)
//   acc    f32           @ 131332   (4)      -- zeroed region ends at 131336
//   idx    [81920] u8    @ 131584
//   pS     [64][256] f32 @ 213504
//   pT     [64][256] f32 @ 279040
#define WS_SUMS_S 0
#define WS_SUMS_T 65536
#define WS_COUNTS 131072
#define WS_ACC    131332
#define WS_ZERO_BYTES 131336
#define WS_IDX    131584
#define WS_PS     213504
#define WS_PT     279040

// ---------------------------------------------------------------------------
// K1: bin index per pixel + histogram.
// invalid = (f < 0) | (f > 64) | !finite  -> bin 64 (dropped downstream).
// (int) truncation toward zero matches jnp astype(int32) for f >= 0.
__global__ __launch_bounds__(256) void k_idx(const float* __restrict__ depth,
                                             unsigned char* __restrict__ idx,
                                             int* __restrict__ counts) {
    __shared__ int h[NB + 1];
    int t = threadIdx.x;
    if (t < NB + 1) h[t] = 0;
    __syncthreads();
    int p = blockIdx.x * 256 + t;
    float f = depth[p] * 64.0f;
    int b;
    if (!(f >= 0.0f) || f > 64.0f) b = NB;            // catches NaN via !(f>=0)
    else { b = (int)f; if (b > NB) b = NB; }
    idx[p] = (unsigned char)b;
    atomicAdd(&h[b], 1);
    __syncthreads();
    if (t < NB + 1 && h[t] != 0) atomicAdd(&counts[t], h[t]);
}

// ---------------------------------------------------------------------------
// K2: per-(n, c, tensor) plane -> per-bin sums. Coalesced float4 reads of the
// contiguous HW plane; bins accumulated in per-wave LDS copies via ds atomics.
__global__ __launch_bounds__(256) void k_sums(const float* __restrict__ predsS,
                                              const float* __restrict__ predsT,
                                              const unsigned char* __restrict__ idx,
                                              float* __restrict__ sumsS,
                                              float* __restrict__ sumsT) {
    int blk = blockIdx.x;            // 2048 blocks
    int tensor = blk & 1;
    int c = (blk >> 1) & 255;
    int n = blk >> 9;
    const float* src = tensor ? predsT : predsS;
    float* dst = tensor ? sumsT : sumsS;
    const float4* plane = (const float4*)(src + (size_t)(n * CCH + c) * HW);
    const uchar4* id = (const uchar4*)(idx + (size_t)n * HW);

    __shared__ float bins[4][NB];    // per-wave privatized
    int t = threadIdx.x;
    for (int i = t; i < 4 * NB; i += 256) ((float*)bins)[i] = 0.0f;
    __syncthreads();
    float* mybins = bins[t >> 6];

    #pragma unroll 4
    for (int k = 0; k < HW / 4 / 256; ++k) {   // 20 iterations
        int i = t + k * 256;
        float4 v = plane[i];
        uchar4 q = id[i];
        if (q.x < NB) atomicAdd(&mybins[q.x], v.x);
        if (q.y < NB) atomicAdd(&mybins[q.y], v.y);
        if (q.z < NB) atomicAdd(&mybins[q.z], v.z);
        if (q.w < NB) atomicAdd(&mybins[q.w], v.w);
    }
    __syncthreads();
    if (t < NB) {
        float s = bins[0][t] + bins[1][t] + bins[2][t] + bins[3][t];
        atomicAdd(&dst[t * CCH + c], s);
    }
}

// ---------------------------------------------------------------------------
// K3: means + L2 normalize -> prototypes. One block per bin, thread = channel.
__global__ __launch_bounds__(256) void k_protos(const float* __restrict__ sumsS,
                                                const float* __restrict__ sumsT,
                                                const int* __restrict__ counts,
                                                float* __restrict__ pS,
                                                float* __restrict__ pT) {
    int b = blockIdx.x, t = threadIdx.x;
    int ci = counts[b];
    float cnt = (float)(ci < 1 ? 1 : ci);
    float mS = sumsS[b * CCH + t] / cnt;
    float mT = sumsT[b * CCH + t] / cnt;
    float ss = mS * mS, st = mT * mT;
    #pragma unroll
    for (int o = 32; o; o >>= 1) {
        ss += __shfl_xor(ss, o, 64);
        st += __shfl_xor(st, o, 64);
    }
    __shared__ float rs[4], rt[4];
    int w = t >> 6;
    if ((t & 63) == 0) { rs[w] = ss; rt[w] = st; }
    __syncthreads();
    float nS = sqrtf(rs[0] + rs[1] + rs[2] + rs[3]);
    float nT = sqrtf(rt[0] + rt[1] + rt[2] + rt[3]);
    pS[b * CCH + t] = mS / fmaxf(nS, 1e-12f);
    pT[b * CCH + t] = mT / fmaxf(nT, 1e-12f);
}

// ---------------------------------------------------------------------------
// K4: Gram matrices + squared-diff partial sums. Block = row i, lane = col j.
__global__ __launch_bounds__(64) void k_sim(const float* __restrict__ pS,
                                            const float* __restrict__ pT,
                                            float* __restrict__ acc) {
    int i = blockIdx.x, j = threadIdx.x;
    const float4* si = (const float4*)(pS + i * CCH);
    const float4* sj = (const float4*)(pS + j * CCH);
    const float4* ti = (const float4*)(pT + i * CCH);
    const float4* tj = (const float4*)(pT + j * CCH);
    float aS = 0.0f, aT = 0.0f;
    #pragma unroll 4
    for (int k = 0; k < CCH / 4; ++k) {
        float4 a = si[k], b = sj[k];
        aS += a.x * b.x + a.y * b.y + a.z * b.z + a.w * b.w;
        float4 cc = ti[k], d = tj[k];
        aT += cc.x * d.x + cc.y * d.y + cc.z * d.z + cc.w * d.w;
    }
    float e = aS - aT;
    e = e * e;
    #pragma unroll
    for (int o = 32; o; o >>= 1) e += __shfl_xor(e, o, 64);
    if (j == 0) atomicAdd(acc, e);
}

// ---------------------------------------------------------------------------
// K5: final scalar
__global__ void k_final(const float* __restrict__ acc, float* __restrict__ out) {
    out[0] = acc[0] * (1.0f / (float)(NB * NB));
}

extern "C" void kernel_launch(void* const* d_in, const int* in_sizes, int n_in,
                              void* d_out, int out_size, void* d_ws, size_t ws_size,
                              hipStream_t stream) {
    const float* predsS = (const float*)d_in[0];
    const float* predsT = (const float*)d_in[1];
    const float* depth  = (const float*)d_in[2];
    char* ws = (char*)d_ws;
    float* sumsS = (float*)(ws + WS_SUMS_S);
    float* sumsT = (float*)(ws + WS_SUMS_T);
    int*   counts = (int*)(ws + WS_COUNTS);
    float* acc   = (float*)(ws + WS_ACC);
    unsigned char* idx = (unsigned char*)(ws + WS_IDX);
    float* pS = (float*)(ws + WS_PS);
    float* pT = (float*)(ws + WS_PT);

    hipMemsetAsync(ws, 0, WS_ZERO_BYTES, stream);
    k_idx<<<NPIX / 256, 256, 0, stream>>>(depth, idx, counts);
    k_sums<<<2048, 256, 0, stream>>>(predsS, predsT, idx, sumsS, sumsT);
    k_protos<<<NB, 256, 0, stream>>>(sumsS, sumsT, counts, pS, pT);
    k_sim<<<NB, 64, 0, stream>>>(pS, pT, acc);
    k_final<<<1, 1, 0, stream>>>(acc, (float*)d_out);
}